// Round 7
// baseline (243.463 us; speedup 1.0000x reference)
//
#include <hip/hip_runtime.h>

typedef unsigned short u16;
typedef __bf16 bf16x8 __attribute__((ext_vector_type(8)));
typedef u16 u16x8 __attribute__((ext_vector_type(8)));
typedef float f32x4 __attribute__((ext_vector_type(4)));

// ws layout (u16 units): (unused) | wqb,wkb,wvb,wob | Qp,Kp,Vt | O
constexpr size_t WQo = 12582912;
constexpr size_t WOo = 15728640;   // WQo + 3 * 1048576
constexpr size_t QPo = 16777216;
constexpr size_t KPo = 20971520;
constexpr size_t VTo = 25165824;
constexpr size_t OOo = 29360128;   // total 33554432 u16 = 64 MB

#define GLD(g, l) __builtin_amdgcn_global_load_lds( \
    (const __attribute__((address_space(1))) void*)(g), \
    (__attribute__((address_space(3))) void*)(l), 16, 0, 0)

__device__ __forceinline__ u16 f2bf(float f) {
  unsigned u = __builtin_bit_cast(unsigned, f);
  u += 0x7fffu + ((u >> 16) & 1u);
  return (u16)(u >> 16);
}

__device__ __forceinline__ f32x4 zero4() {
  f32x4 z = {0.f, 0.f, 0.f, 0.f};
  return z;
}

__device__ __forceinline__ f32x4 mfma16(u16x8 a, u16x8 b, f32x4 c) {
  return __builtin_amdgcn_mfma_f32_16x16x32_bf16(
      __builtin_bit_cast(bf16x8, a), __builtin_bit_cast(bf16x8, b), c, 0, 0, 0);
}

__device__ __forceinline__ u16x8 cvt8(f32x4 lo, f32x4 hi) {
  u16x8 r;
  r[0] = f2bf(lo[0]); r[1] = f2bf(lo[1]); r[2] = f2bf(lo[2]); r[3] = f2bf(lo[3]);
  r[4] = f2bf(hi[0]); r[5] = f2bf(hi[1]); r[6] = f2bf(hi[2]); r[7] = f2bf(hi[3]);
  return r;
}

// ------------------------------------------------------------ weight cast only
__global__ __launch_bounds__(256) void cast_w(
    const float4* __restrict__ wq, const float4* __restrict__ wk,
    const float4* __restrict__ wv, const float4* __restrict__ wo,
    ushort4* __restrict__ dst)
{
  int i = blockIdx.x * 256 + threadIdx.x;
  constexpr int WN = 262144;    // 1024*1024/4
  float4 val;
  if (i < WN)          val = wq[i];
  else if (i < 2 * WN) val = wk[i - WN];
  else if (i < 3 * WN) val = wv[i - 2 * WN];
  else                 val = wo[i - 3 * WN];
  ushort4 o;
  o.x = f2bf(val.x); o.y = f2bf(val.y); o.z = f2bf(val.z); o.w = f2bf(val.w);
  dst[i] = o;
}

// ---------------- GEMM core (BK=32, dbuf, hoisted, proven LDS geometry) ------
// LDS (R3/R5, measured 0 conflicts): two matrix rows per 128 B LDS row; chunk
// c = (m&1)*4 + k4 stored at slot p = c ^ ((m>>1)&7). Double-buffered, one
// barrier per k-iter, all addresses hoisted.
// AFUSE: A is fp32 in global; staged via buffer_load -> f2bf regs ->
// ds_write_b128 into the SAME bf16 geometry (LDS stays bf16, unlike R4).
// modes: 0: bf16 [B,H,S,DK]   1: bf16 [B,H,DK,S] (V^T, ushort4)   3: fp32 [M,N]
template <int TM, bool AFUSE>
__device__ __forceinline__ void gemm_core(
    const void* __restrict__ Ap, const u16* __restrict__ W,
    const float* __restrict__ bias, void* __restrict__ outp,
    int m0, int n0, int mode)
{
  constexpr int Kd = 1024;
  constexpr int BM = TM * 32;
  constexpr int AC = BM / 64;        // bf16-GLD rounds for A tile
  constexpr int ACH = BM / 64;       // fused: 16B chunks per thread
  constexpr int ASZ = BM * 32;
  __shared__ alignas(16) u16 As[2 * ASZ];
  __shared__ alignas(16) u16 Bs[2 * 4096];
  const int tid = threadIdx.x;
  const int wave = tid >> 6, lane = tid & 63;
  const int q4 = lane >> 4, l15 = lane & 15;
  const int wm = (wave >> 1) * (TM * 16), wn = (wave & 1) * 64;

  // hoisted A staging
  const float* afsrc[AFUSE ? ACH : 1]; int afdst[AFUSE ? ACH : 1];
  const u16*   asrc [AFUSE ? 1 : AC]; int adst [AFUSE ? 1 : AC];
  if (AFUSE) {
#pragma unroll
    for (int u = 0; u < ACH; ++u) {
      const int ci = u * 256 + tid;          // chunk id 0..BM*4-1
      const int m = ci >> 2, k4 = ci & 3;
      const int lr = m >> 1;
      const int p = ((m & 1) * 4 + k4) ^ (lr & 7);
      afsrc[u] = (const float*)Ap + (size_t)(m0 + m) * Kd + k4 * 8;
      afdst[u] = lr * 64 + p * 8;
    }
  } else {
#pragma unroll
    for (int t = 0; t < AC; ++t) {
      const int pos = t * 256 + tid;
      const int lr = pos >> 3, p = pos & 7;
      const int c = p ^ (lr & 7);
      asrc[t] = (const u16*)Ap + (size_t)(m0 + lr * 2 + (c >> 2)) * Kd + (c & 3) * 8;
      adst[t] = pos * 8;
    }
  }
  const u16* bsrc[2]; int bdst[2];
#pragma unroll
  for (int t = 0; t < 2; ++t) {
    const int pos = t * 256 + tid;
    const int lr = pos >> 3, p = pos & 7;
    const int c = p ^ (lr & 7);
    bsrc[t] = W + (size_t)(n0 + lr * 2 + (c >> 2)) * Kd + (c & 3) * 8;
    bdst[t] = pos * 8;
  }
  int aoff[TM], boff[4];
#pragma unroll
  for (int i = 0; i < TM; ++i) {
    const int m = wm + i * 16 + l15;
    const int lr = m >> 1;
    const int p = ((m & 1) * 4 + q4) ^ (lr & 7);
    aoff[i] = lr * 64 + p * 8;
  }
#pragma unroll
  for (int j = 0; j < 4; ++j) {
    const int m = wn + j * 16 + l15;
    const int lr = m >> 1;
    const int p = ((m & 1) * 4 + q4) ^ (lr & 7);
    boff[j] = lr * 64 + p * 8;
  }

  f32x4 acc[TM][4];
#pragma unroll
  for (int i = 0; i < TM; ++i)
#pragma unroll
    for (int j = 0; j < 4; ++j) acc[i][j] = zero4();

  // prologue: stage k-tile 0 into buffer 0
  if (AFUSE) {
#pragma unroll
    for (int u = 0; u < ACH; ++u) {
      f32x4 lo = *(const f32x4*)(afsrc[u]);
      f32x4 hi = *(const f32x4*)(afsrc[u] + 4);
      *(u16x8*)&As[afdst[u]] = cvt8(lo, hi);
    }
  } else {
#pragma unroll
    for (int t = 0; t < AC; ++t) GLD(asrc[t], As + adst[t]);
  }
#pragma unroll
  for (int t = 0; t < 2; ++t) GLD(bsrc[t], Bs + bdst[t]);

  for (int it = 0; it < 32; ++it) {
    const int buf = it & 1;
    __syncthreads();             // buffer `buf` ready; buffer buf^1 consumed
    const int kt = (it + 1) * 32;
    const int ob = buf ^ 1;
    f32x4 lo[AFUSE ? ACH : 1], hi[AFUSE ? ACH : 1];
    if (it < 31) {
      if (AFUSE) {
#pragma unroll
        for (int u = 0; u < ACH; ++u) {
          lo[u] = *(const f32x4*)(afsrc[u] + kt);
          hi[u] = *(const f32x4*)(afsrc[u] + kt + 4);
        }
      } else {
#pragma unroll
        for (int t = 0; t < AC; ++t) GLD(asrc[t] + kt, As + ob * ASZ + adst[t]);
      }
#pragma unroll
      for (int t = 0; t < 2; ++t) GLD(bsrc[t] + kt, Bs + ob * 4096 + bdst[t]);
    }
    const u16* Ab = As + buf * ASZ;
    const u16* Bb = Bs + buf * 4096;
    u16x8 af[TM], bfv[4];
#pragma unroll
    for (int i = 0; i < TM; ++i) af[i] = *(const u16x8*)&Ab[aoff[i]];
#pragma unroll
    for (int j = 0; j < 4; ++j) bfv[j] = *(const u16x8*)&Bb[boff[j]];
#pragma unroll
    for (int i = 0; i < TM; ++i)
#pragma unroll
      for (int j = 0; j < 4; ++j)
        acc[i][j] = mfma16(af[i], bfv[j], acc[i][j]);
    if (AFUSE && it < 31) {
#pragma unroll
      for (int u = 0; u < ACH; ++u)
        *(u16x8*)&As[ob * ASZ + afdst[u]] = cvt8(lo[u], hi[u]);
    }
  }

  // epilogue: C/D layout col = l15, row = q4*4 + r
#pragma unroll
  for (int i = 0; i < TM; ++i) {
    const int mb = m0 + wm + i * 16 + q4 * 4;
#pragma unroll
    for (int j = 0; j < 4; ++j) {
      const int col = n0 + wn + j * 16 + l15;
      const float bsv = bias[col];
      if (mode == 1) {
        const int bb = mb >> 11, s = mb & 2047, hh = col >> 6, dk = col & 63;
        ushort4 pk;
        pk.x = f2bf(acc[i][j][0] + bsv);
        pk.y = f2bf(acc[i][j][1] + bsv);
        pk.z = f2bf(acc[i][j][2] + bsv);
        pk.w = f2bf(acc[i][j][3] + bsv);
        *(ushort4*)&((u16*)outp)[((size_t)(bb * 16 + hh) * 64 + dk) * 2048 + s] = pk;
      } else {
#pragma unroll
        for (int r = 0; r < 4; ++r) {
          const float val = acc[i][j][r] + bsv;
          const int m = mb + r;
          if (mode == 0) {
            const int bb = m >> 11, s = m & 2047, hh = col >> 6, dk = col & 63;
            ((u16*)outp)[((size_t)(bb * 16 + hh) * 2048 + s) * 64 + dk] = f2bf(val);
          } else {
            ((float*)outp)[(size_t)m * 1024 + col] = val;
          }
        }
      }
    }
  }
}

// 1-D grid 768. Blocks sharing an A-tile (same by) have ids congruent mod 8
// -> same XCD (R3: FETCH 101 -> 37 MB). A read as fp32 directly (fused cast).
__global__ __launch_bounds__(256) void proj_gemm(
    const float* __restrict__ q, const float* __restrict__ k,
    const float* __restrict__ v, u16* __restrict__ ws,
    const float* __restrict__ bq, const float* __restrict__ bk,
    const float* __restrict__ bv)
{
  const int id = blockIdx.x;
  const int z = id >> 8, rem = id & 255;
  const int bx = rem >> 5, by = rem & 31;
  const float* A = (z == 0) ? q : ((z == 1) ? k : v);
  const u16* W = ws + WQo + (size_t)z * 1048576;
  const float* bias = (z == 0) ? bq : ((z == 1) ? bk : bv);
  u16* outp = ws + QPo + (size_t)z * 4194304;
  gemm_core<4, true>(A, W, bias, outp, by * 128, bx * 128, (z == 2) ? 1 : 0);
}

// 1-D grid 256, TM=4 (same structure as one proj GEMM slice).
// Same-A blocks (same by) congruent mod 8 -> same XCD.
__global__ __launch_bounds__(256) void out_gemm(
    const u16* __restrict__ ws, const float* __restrict__ bo, float* __restrict__ out)
{
  const int id = blockIdx.x;
  const int bx = id >> 5, by = id & 31;
  gemm_core<4, false>(ws + OOo, ws + WOo, bo, out, by * 128, bx * 128, 3);
}

// ------------------------------------------------------------- flash attention
// Paired q-tiles: block x handles q-tiles a=x and b=31-x over one shared K/V
// k-loop (33 k-tiles per block, perfectly balanced). No-max softmax, deferred
// l reduction, double-buffered K/V staging. grid (16, B*H).
__global__ __launch_bounds__(256) void flash_attn(u16* __restrict__ ws)
{
  constexpr int S = 2048;
  const int a = blockIdx.x;         // 0..15
  const int b = 31 - blockIdx.x;    // 16..31
  const int bh = blockIdx.y;
  const int bb = bh >> 4, h = bh & 15;
  const int tid = threadIdx.x;
  const int wave = tid >> 6, lane = tid & 63;
  const int q4 = lane >> 4, l15 = lane & 15;

  __shared__ u16 QsA[64 * 64];      // wave strip aliased as Ps after qfA read
  __shared__ u16 QsB[64 * 64];
  __shared__ u16 Ks[2][64 * 64];
  __shared__ u16 Vs[2][64 * 64];    // [dk][s] within tile

  const u16* Qg = ws + QPo + (size_t)bh * S * 64;
  const u16* Kg = ws + KPo + (size_t)bh * S * 64;
  const u16* Vg = ws + VTo + (size_t)bh * 64 * S;
  u16* Og = ws + OOo;

  const int ch0 = wave * 128 + lane;
  const int ch1 = ch0 + 64;
  const int r0 = ch0 >> 3, c0 = (ch0 & 7) ^ (r0 & 7);
  const int r1 = ch1 >> 3, c1 = (ch1 & 7) ^ (r1 & 7);

  GLD(Qg + (size_t)(a * 64 + r0) * 64 + c0 * 8, QsA + wave * 1024);
  GLD(Qg + (size_t)(a * 64 + r1) * 64 + c1 * 8, QsA + wave * 1024 + 512);
  GLD(Qg + (size_t)(b * 64 + r0) * 64 + c0 * 8, QsB + wave * 1024);
  GLD(Qg + (size_t)(b * 64 + r1) * 64 + c1 * 8, QsB + wave * 1024 + 512);
  GLD(Kg + (size_t)r0 * 64 + c0 * 8, Ks[0] + wave * 1024);
  GLD(Kg + (size_t)r1 * 64 + c1 * 8, Ks[0] + wave * 1024 + 512);
  GLD(Vg + (size_t)r0 * S + c0 * 8, Vs[0] + wave * 1024);
  GLD(Vg + (size_t)r1 * S + c1 * 8, Vs[0] + wave * 1024 + 512);
  __syncthreads();

  u16x8 qfA[2], qfB[2];
  {
    const int row = wave * 16 + l15;
#pragma unroll
    for (int kk = 0; kk < 2; ++kk) {
      const int c = (kk * 4 + q4) ^ (row & 7);
      qfA[kk] = *(const u16x8*)&QsA[row * 64 + c * 8];
      qfB[kk] = *(const u16x8*)&QsB[row * 64 + c * 8];
    }
  }
  u16* Ps = QsA + wave * 1024;   // wave's own Q strip, consumed above

  f32x4 oA[4], oB[4];
  float lA[4], lB[4];
#pragma unroll
  for (int j = 0; j < 4; ++j) { oA[j] = zero4(); oB[j] = zero4(); }
#pragma unroll
  for (int r = 0; r < 4; ++r) { lA[r] = 0.f; lB[r] = 0.f; }

  for (int kt = 0; kt <= b; ++kt) {
    const u16* Ksb = Ks[kt & 1];
    const u16* Vsb = Vs[kt & 1];
    if (kt < b) {
      const u16* Kt = Kg + (size_t)(kt + 1) * 64 * 64;
      u16* Kd = Ks[(kt + 1) & 1];
      u16* Vd = Vs[(kt + 1) & 1];
      GLD(Kt + (size_t)r0 * 64 + c0 * 8, Kd + wave * 1024);
      GLD(Kt + (size_t)r1 * 64 + c1 * 8, Kd + wave * 1024 + 512);
      GLD(Vg + (size_t)r0 * S + (kt + 1) * 64 + c0 * 8, Vd + wave * 1024);
      GLD(Vg + (size_t)r1 * S + (kt + 1) * 64 + c1 * 8, Vd + wave * 1024 + 512);
    }

    auto process = [&](const u16x8* qf, f32x4* o_acc, float* l_p, int qt, bool diag) {
      f32x4 sf[4];
#pragma unroll
      for (int j = 0; j < 4; ++j) {
        f32x4 z = zero4();
        const int row = j * 16 + l15;
#pragma unroll
        for (int kk = 0; kk < 2; ++kk) {
          const int c = (kk * 4 + q4) ^ (row & 7);
          z = mfma16(qf[kk], *(const u16x8*)&Ksb[row * 64 + c * 8], z);
        }
        sf[j] = z;
      }
      if (diag) {
        const int rowg0 = qt * 64 + wave * 16 + q4 * 4;
#pragma unroll
        for (int j = 0; j < 4; ++j) {
          const int colg = kt * 64 + j * 16 + l15;
#pragma unroll
          for (int r = 0; r < 4; ++r) {
            float val = sf[j][r] * 0.125f;
            if (colg > rowg0 + r) val = -__builtin_inff();
            sf[j][r] = __expf(val);
          }
        }
      } else {
#pragma unroll
        for (int j = 0; j < 4; ++j)
#pragma unroll
          for (int r = 0; r < 4; ++r)
            sf[j][r] = __expf(sf[j][r] * 0.125f);
      }
#pragma unroll
      for (int j = 0; j < 4; ++j)
#pragma unroll
        for (int r = 0; r < 4; ++r) l_p[r] += sf[j][r];

#pragma unroll
      for (int j = 0; j < 4; ++j)
#pragma unroll
        for (int r = 0; r < 4; ++r) {
          const int m = q4 * 4 + r;
          const int srow = j * 16 + l15;
          const int pos = m * 64 + (((srow >> 3) ^ (m & 7)) << 3) + (srow & 7);
          Ps[pos] = f2bf(sf[j][r]);
        }
      u16x8 pf[2];
#pragma unroll
      for (int kk = 0; kk < 2; ++kk) {
        const int c = (kk * 4 + q4) ^ (l15 & 7);
        pf[kk] = *(const u16x8*)&Ps[l15 * 64 + c * 8];
      }
#pragma unroll
      for (int j = 0; j < 4; ++j) {
        const int row = j * 16 + l15;   // dk row of Vs
#pragma unroll
        for (int kk = 0; kk < 2; ++kk) {
          const int c = (kk * 4 + q4) ^ (row & 7);
          o_acc[j] = mfma16(pf[kk], *(const u16x8*)&Vsb[row * 64 + c * 8], o_acc[j]);
        }
      }
    };

    process(qfB, oB, lB, b, kt == b);
    if (kt <= a) process(qfA, oA, lA, a, kt == a);
    __syncthreads();
  }

#pragma unroll
  for (int off = 1; off < 16; off <<= 1)
#pragma unroll
    for (int r = 0; r < 4; ++r) {
      lA[r] += __shfl_xor(lA[r], off, 64);
      lB[r] += __shfl_xor(lB[r], off, 64);
    }

#pragma unroll
  for (int r = 0; r < 4; ++r) {
    const float invA = 1.f / lA[r];
    const float invB = 1.f / lB[r];
    const int sA = a * 64 + wave * 16 + q4 * 4 + r;
    const int sB = b * 64 + wave * 16 + q4 * 4 + r;
    const size_t baseA = ((size_t)(bb * 2048 + sA)) * 1024 + h * 64;
    const size_t baseB = ((size_t)(bb * 2048 + sB)) * 1024 + h * 64;
#pragma unroll
    for (int j = 0; j < 4; ++j) {
      Og[baseA + j * 16 + l15] = f2bf(oA[j][r] * invA);
      Og[baseB + j * 16 + l15] = f2bf(oB[j][r] * invB);
    }
  }
}

// ----------------------------------------------------------------- launch
extern "C" void kernel_launch(void* const* d_in, const int* in_sizes, int n_in,
                              void* d_out, int out_size, void* d_ws, size_t ws_size,
                              hipStream_t stream)
{
  const float* q  = (const float*)d_in[0];
  const float* k  = (const float*)d_in[1];
  const float* v  = (const float*)d_in[2];
  // d_in[3] = mask (causal by construction, unused)
  const float* wq = (const float*)d_in[4];
  const float* bq = (const float*)d_in[5];
  const float* wk = (const float*)d_in[6];
  const float* bk = (const float*)d_in[7];
  const float* wv = (const float*)d_in[8];
  const float* bv = (const float*)d_in[9];
  const float* wo = (const float*)d_in[10];
  const float* bo = (const float*)d_in[11];
  u16* ws = (u16*)d_ws;
  float* out = (float*)d_out;

  cast_w<<<4096, 256, 0, stream>>>(
      (const float4*)wq, (const float4*)wk, (const float4*)wv, (const float4*)wo,
      (ushort4*)(ws + WQo));
  proj_gemm<<<768, 256, 0, stream>>>(q, k, v, ws, bq, bk, bv);
  flash_attn<<<dim3(16, 32), 256, 0, stream>>>(ws);
  out_gemm<<<256, 256, 0, stream>>>(ws, bo, out);
}

// Round 8
// 232.227 us; speedup vs baseline: 1.0484x; 1.0484x over previous
//
#include <hip/hip_runtime.h>

typedef unsigned short u16;
typedef __bf16 bf16x8 __attribute__((ext_vector_type(8)));
typedef u16 u16x8 __attribute__((ext_vector_type(8)));
typedef float f32x4 __attribute__((ext_vector_type(4)));

// ws layout (u16 units): qb,kb,vb | wqb,wkb,wvb,wob | Qp,Kp,Vt | O
constexpr size_t WQo = 12582912;   // 3 * 4194304
constexpr size_t WOo = 15728640;   // WQo + 3 * 1048576
constexpr size_t QPo = 16777216;
constexpr size_t KPo = 20971520;
constexpr size_t VTo = 25165824;
constexpr size_t OOo = 29360128;   // total 33554432 u16 = 64 MB

#define GLD(g, l) __builtin_amdgcn_global_load_lds( \
    (const __attribute__((address_space(1))) void*)(g), \
    (__attribute__((address_space(3))) void*)(l), 16, 0, 0)

__device__ __forceinline__ u16 f2bf(float f) {
  unsigned u = __builtin_bit_cast(unsigned, f);
  u += 0x7fffu + ((u >> 16) & 1u);
  return (u16)(u >> 16);
}

__device__ __forceinline__ f32x4 zero4() {
  f32x4 z = {0.f, 0.f, 0.f, 0.f};
  return z;
}

__device__ __forceinline__ f32x4 mfma16(u16x8 a, u16x8 b, f32x4 c) {
  return __builtin_amdgcn_mfma_f32_16x16x32_bf16(
      __builtin_bit_cast(bf16x8, a), __builtin_bit_cast(bf16x8, b), c, 0, 0, 0);
}

// ---------------------------------------------------------------- cast kernel
__global__ __launch_bounds__(256) void cast_all(
    const float4* __restrict__ q, const float4* __restrict__ k, const float4* __restrict__ v,
    const float4* __restrict__ wq, const float4* __restrict__ wk,
    const float4* __restrict__ wv, const float4* __restrict__ wo,
    ushort4* __restrict__ dst)
{
  int i = blockIdx.x * 256 + threadIdx.x;
  constexpr int QN = 1048576;   // 4096*1024/4
  constexpr int WN = 262144;    // 1024*1024/4
  float4 val;
  if (i < QN)            val = q[i];
  else if (i < 2 * QN)   val = k[i - QN];
  else if (i < 3 * QN)   val = v[i - 2 * QN];
  else {
    int j = i - 3 * QN;
    if (j < WN)          val = wq[j];
    else if (j < 2 * WN) val = wk[j - WN];
    else if (j < 3 * WN) val = wv[j - 2 * WN];
    else                 val = wo[j - 3 * WN];
  }
  ushort4 o;
  o.x = f2bf(val.x); o.y = f2bf(val.y); o.z = f2bf(val.z); o.w = f2bf(val.w);
  dst[i] = o;
}

// ------------- GEMM core (BK=32, dbuf, hoisted, proven LDS geometry; R5) -----
// LDS (R3/R5, measured 0 conflicts): two matrix rows per 128 B LDS row; chunk
// c = (m&1)*4 + k4 stored at slot p = c ^ ((m>>1)&7). Double-buffered, one
// barrier per k-iter, all addresses hoisted, A staged bf16 via GLD (R6 proof:
// any VGPR-routed A path loses ~20 us to the DMA path).
// modes: 0: bf16 [B,H,S,DK]   1: bf16 [B,H,DK,S] (V^T, ushort4)   3: fp32 [M,N]
template <int TM, int BN>
__device__ __forceinline__ void gemm_core(
    const u16* __restrict__ A, const u16* __restrict__ W,
    const float* __restrict__ bias, void* __restrict__ outp,
    int m0, int n0, int mode)
{
  constexpr int Kd = 1024;
  constexpr int BM = TM * 32;
  constexpr int NJ = BN / 32;        // B fragment count per wave
  constexpr int AC = BM / 64;        // A staging GLD rounds (256 chunks each)
  constexpr int BC = BN / 64;        // B staging GLD rounds
  constexpr int ASZ = BM * 32;       // u16 per A buffer
  constexpr int BSZ = BN * 32;
  __shared__ alignas(16) u16 As[2 * ASZ];
  __shared__ alignas(16) u16 Bs[2 * BSZ];
  const int tid = threadIdx.x;
  const int wave = tid >> 6, lane = tid & 63;
  const int q4 = lane >> 4, l15 = lane & 15;
  const int wm = (wave >> 1) * (TM * 16), wn = (wave & 1) * (BN / 2);

  // hoisted staging sources (swizzled) + LDS offsets
  const u16* asrc[AC]; int adst[AC];
#pragma unroll
  for (int t = 0; t < AC; ++t) {
    const int pos = t * 256 + tid;
    const int lr = pos >> 3, p = pos & 7;
    const int c = p ^ (lr & 7);
    asrc[t] = A + (size_t)(m0 + lr * 2 + (c >> 2)) * Kd + (c & 3) * 8;
    adst[t] = pos * 8;
  }
  const u16* bsrc[BC]; int bdst[BC];
#pragma unroll
  for (int t = 0; t < BC; ++t) {
    const int pos = t * 256 + tid;
    const int lr = pos >> 3, p = pos & 7;
    const int c = p ^ (lr & 7);
    bsrc[t] = W + (size_t)(n0 + lr * 2 + (c >> 2)) * Kd + (c & 3) * 8;
    bdst[t] = pos * 8;
  }
  // hoisted fragment read offsets
  int aoff[TM], boff[NJ];
#pragma unroll
  for (int i = 0; i < TM; ++i) {
    const int m = wm + i * 16 + l15;
    const int lr = m >> 1;
    const int p = ((m & 1) * 4 + q4) ^ (lr & 7);
    aoff[i] = lr * 64 + p * 8;
  }
#pragma unroll
  for (int j = 0; j < NJ; ++j) {
    const int m = wn + j * 16 + l15;
    const int lr = m >> 1;
    const int p = ((m & 1) * 4 + q4) ^ (lr & 7);
    boff[j] = lr * 64 + p * 8;
  }

  f32x4 acc[TM][NJ];
#pragma unroll
  for (int i = 0; i < TM; ++i)
#pragma unroll
    for (int j = 0; j < NJ; ++j) acc[i][j] = zero4();

  // prologue: stage k-tile 0 into buffer 0
#pragma unroll
  for (int t = 0; t < AC; ++t) GLD(asrc[t], As + adst[t]);
#pragma unroll
  for (int t = 0; t < BC; ++t) GLD(bsrc[t], Bs + bdst[t]);

  for (int it = 0; it < 32; ++it) {
    const int buf = it & 1;
    __syncthreads();             // buffer `buf` ready; buffer buf^1 consumed
    if (it < 31) {
      const int kt = (it + 1) * 32;
      const int ob = buf ^ 1;
#pragma unroll
      for (int t = 0; t < AC; ++t) GLD(asrc[t] + kt, As + ob * ASZ + adst[t]);
#pragma unroll
      for (int t = 0; t < BC; ++t) GLD(bsrc[t] + kt, Bs + ob * BSZ + bdst[t]);
    }
    const u16* Ab = As + buf * ASZ;
    const u16* Bb = Bs + buf * BSZ;
    u16x8 af[TM], bfv[NJ];
#pragma unroll
    for (int i = 0; i < TM; ++i) af[i] = *(const u16x8*)&Ab[aoff[i]];
#pragma unroll
    for (int j = 0; j < NJ; ++j) bfv[j] = *(const u16x8*)&Bb[boff[j]];
#pragma unroll
    for (int i = 0; i < TM; ++i)
#pragma unroll
      for (int j = 0; j < NJ; ++j)
        acc[i][j] = mfma16(af[i], bfv[j], acc[i][j]);
  }

  // epilogue: C/D layout col = l15, row = q4*4 + r
#pragma unroll
  for (int i = 0; i < TM; ++i) {
    const int mb = m0 + wm + i * 16 + q4 * 4;
#pragma unroll
    for (int j = 0; j < NJ; ++j) {
      const int col = n0 + wn + j * 16 + l15;
      const float bsv = bias[col];
      if (mode == 1) {
        // V^T: r = 0..3 are consecutive s -> pack ushort4
        const int bb = mb >> 11, s = mb & 2047, hh = col >> 6, dk = col & 63;
        ushort4 pk;
        pk.x = f2bf(acc[i][j][0] + bsv);
        pk.y = f2bf(acc[i][j][1] + bsv);
        pk.z = f2bf(acc[i][j][2] + bsv);
        pk.w = f2bf(acc[i][j][3] + bsv);
        *(ushort4*)&((u16*)outp)[((size_t)(bb * 16 + hh) * 64 + dk) * 2048 + s] = pk;
      } else {
#pragma unroll
        for (int r = 0; r < 4; ++r) {
          const float val = acc[i][j][r] + bsv;
          const int m = mb + r;
          if (mode == 0) {
            const int bb = m >> 11, s = m & 2047, hh = col >> 6, dk = col & 63;
            ((u16*)outp)[((size_t)(bb * 16 + hh) * 2048 + s) * 64 + dk] = f2bf(val);
          } else {
            ((float*)outp)[(size_t)m * 1024 + col] = val;
          }
        }
      }
    }
  }
}

// 1-D grid 768. Blocks sharing an A-tile (same by) have ids congruent mod 8
// -> same XCD -> A fetched once per XCD (R3: FETCH 101 -> 37 MB).
__global__ __launch_bounds__(256) void proj_gemm(
    u16* __restrict__ ws, const float* __restrict__ bq,
    const float* __restrict__ bk, const float* __restrict__ bv)
{
  const int id = blockIdx.x;
  const int z = id >> 8, rem = id & 255;
  const int bx = rem >> 5, by = rem & 31;
  const u16* A = ws + (size_t)z * 4194304;
  const u16* W = ws + WQo + (size_t)z * 1048576;
  const float* bias = (z == 0) ? bq : ((z == 1) ? bk : bv);
  u16* outp = ws + QPo + (size_t)z * 4194304;
  gemm_core<4, 128>(A, W, bias, outp, by * 128, bx * 128, (z == 2) ? 1 : 0);
}

// 64x64 tiles, 1-D grid 1024 (4 blocks/CU, 16 waves/CU). Blocks sharing an
// A-tile (same by) differ by 64 in id -> same XCD.
__global__ __launch_bounds__(256) void out_gemm(
    const u16* __restrict__ ws, const float* __restrict__ bo, float* __restrict__ out)
{
  const int id = blockIdx.x;
  const int bx = id >> 6, by = id & 63;
  gemm_core<2, 64>(ws + OOo, ws + WOo, bo, out, by * 64, bx * 64, 3);
}

// ------------------------------------------------------------- flash attention
// Paired q-tiles: block x handles q-tiles a=x and b=31-x over one shared K/V
// k-loop (33 k-tiles per block, perfectly balanced). No-max softmax, deferred
// l reduction, double-buffered K/V staging. grid (16, B*H).
__global__ __launch_bounds__(256) void flash_attn(u16* __restrict__ ws)
{
  constexpr int S = 2048;
  const int a = blockIdx.x;         // 0..15
  const int b = 31 - blockIdx.x;    // 16..31
  const int bh = blockIdx.y;
  const int bb = bh >> 4, h = bh & 15;
  const int tid = threadIdx.x;
  const int wave = tid >> 6, lane = tid & 63;
  const int q4 = lane >> 4, l15 = lane & 15;

  __shared__ u16 QsA[64 * 64];      // wave strip aliased as Ps after qfA read
  __shared__ u16 QsB[64 * 64];
  __shared__ u16 Ks[2][64 * 64];
  __shared__ u16 Vs[2][64 * 64];    // [dk][s] within tile

  const u16* Qg = ws + QPo + (size_t)bh * S * 64;
  const u16* Kg = ws + KPo + (size_t)bh * S * 64;
  const u16* Vg = ws + VTo + (size_t)bh * 64 * S;
  u16* Og = ws + OOo;

  const int ch0 = wave * 128 + lane;
  const int ch1 = ch0 + 64;
  const int r0 = ch0 >> 3, c0 = (ch0 & 7) ^ (r0 & 7);
  const int r1 = ch1 >> 3, c1 = (ch1 & 7) ^ (r1 & 7);

  GLD(Qg + (size_t)(a * 64 + r0) * 64 + c0 * 8, QsA + wave * 1024);
  GLD(Qg + (size_t)(a * 64 + r1) * 64 + c1 * 8, QsA + wave * 1024 + 512);
  GLD(Qg + (size_t)(b * 64 + r0) * 64 + c0 * 8, QsB + wave * 1024);
  GLD(Qg + (size_t)(b * 64 + r1) * 64 + c1 * 8, QsB + wave * 1024 + 512);
  GLD(Kg + (size_t)r0 * 64 + c0 * 8, Ks[0] + wave * 1024);
  GLD(Kg + (size_t)r1 * 64 + c1 * 8, Ks[0] + wave * 1024 + 512);
  GLD(Vg + (size_t)r0 * S + c0 * 8, Vs[0] + wave * 1024);
  GLD(Vg + (size_t)r1 * S + c1 * 8, Vs[0] + wave * 1024 + 512);
  __syncthreads();

  u16x8 qfA[2], qfB[2];
  {
    const int row = wave * 16 + l15;
#pragma unroll
    for (int kk = 0; kk < 2; ++kk) {
      const int c = (kk * 4 + q4) ^ (row & 7);
      qfA[kk] = *(const u16x8*)&QsA[row * 64 + c * 8];
      qfB[kk] = *(const u16x8*)&QsB[row * 64 + c * 8];
    }
  }
  u16* Ps = QsA + wave * 1024;   // wave's own Q strip, consumed above

  f32x4 oA[4], oB[4];
  float lA[4], lB[4];
#pragma unroll
  for (int j = 0; j < 4; ++j) { oA[j] = zero4(); oB[j] = zero4(); }
#pragma unroll
  for (int r = 0; r < 4; ++r) { lA[r] = 0.f; lB[r] = 0.f; }

  for (int kt = 0; kt <= b; ++kt) {
    const u16* Ksb = Ks[kt & 1];
    const u16* Vsb = Vs[kt & 1];
    if (kt < b) {
      const u16* Kt = Kg + (size_t)(kt + 1) * 64 * 64;
      u16* Kd = Ks[(kt + 1) & 1];
      u16* Vd = Vs[(kt + 1) & 1];
      GLD(Kt + (size_t)r0 * 64 + c0 * 8, Kd + wave * 1024);
      GLD(Kt + (size_t)r1 * 64 + c1 * 8, Kd + wave * 1024 + 512);
      GLD(Vg + (size_t)r0 * S + (kt + 1) * 64 + c0 * 8, Vd + wave * 1024);
      GLD(Vg + (size_t)r1 * S + (kt + 1) * 64 + c1 * 8, Vd + wave * 1024 + 512);
    }

    auto process = [&](const u16x8* qf, f32x4* o_acc, float* l_p, int qt, bool diag) {
      f32x4 sf[4];
#pragma unroll
      for (int j = 0; j < 4; ++j) {
        f32x4 z = zero4();
        const int row = j * 16 + l15;
#pragma unroll
        for (int kk = 0; kk < 2; ++kk) {
          const int c = (kk * 4 + q4) ^ (row & 7);
          z = mfma16(qf[kk], *(const u16x8*)&Ksb[row * 64 + c * 8], z);
        }
        sf[j] = z;
      }
      if (diag) {
        const int rowg0 = qt * 64 + wave * 16 + q4 * 4;
#pragma unroll
        for (int j = 0; j < 4; ++j) {
          const int colg = kt * 64 + j * 16 + l15;
#pragma unroll
          for (int r = 0; r < 4; ++r) {
            float val = sf[j][r] * 0.125f;
            if (colg > rowg0 + r) val = -__builtin_inff();
            sf[j][r] = __expf(val);
          }
        }
      } else {
#pragma unroll
        for (int j = 0; j < 4; ++j)
#pragma unroll
          for (int r = 0; r < 4; ++r)
            sf[j][r] = __expf(sf[j][r] * 0.125f);
      }
#pragma unroll
      for (int j = 0; j < 4; ++j)
#pragma unroll
        for (int r = 0; r < 4; ++r) l_p[r] += sf[j][r];

#pragma unroll
      for (int j = 0; j < 4; ++j)
#pragma unroll
        for (int r = 0; r < 4; ++r) {
          const int m = q4 * 4 + r;
          const int srow = j * 16 + l15;
          const int pos = m * 64 + (((srow >> 3) ^ (m & 7)) << 3) + (srow & 7);
          Ps[pos] = f2bf(sf[j][r]);
        }
      u16x8 pf[2];
#pragma unroll
      for (int kk = 0; kk < 2; ++kk) {
        const int c = (kk * 4 + q4) ^ (l15 & 7);
        pf[kk] = *(const u16x8*)&Ps[l15 * 64 + c * 8];
      }
#pragma unroll
      for (int j = 0; j < 4; ++j) {
        const int row = j * 16 + l15;   // dk row of Vs
#pragma unroll
        for (int kk = 0; kk < 2; ++kk) {
          const int c = (kk * 4 + q4) ^ (row & 7);
          o_acc[j] = mfma16(pf[kk], *(const u16x8*)&Vsb[row * 64 + c * 8], o_acc[j]);
        }
      }
    };

    process(qfB, oB, lB, b, kt == b);
    if (kt <= a) process(qfA, oA, lA, a, kt == a);
    __syncthreads();
  }

#pragma unroll
  for (int off = 1; off < 16; off <<= 1)
#pragma unroll
    for (int r = 0; r < 4; ++r) {
      lA[r] += __shfl_xor(lA[r], off, 64);
      lB[r] += __shfl_xor(lB[r], off, 64);
    }

#pragma unroll
  for (int r = 0; r < 4; ++r) {
    const float invA = 1.f / lA[r];
    const float invB = 1.f / lB[r];
    const int sA = a * 64 + wave * 16 + q4 * 4 + r;
    const int sB = b * 64 + wave * 16 + q4 * 4 + r;
    const size_t baseA = ((size_t)(bb * 2048 + sA)) * 1024 + h * 64;
    const size_t baseB = ((size_t)(bb * 2048 + sB)) * 1024 + h * 64;
#pragma unroll
    for (int j = 0; j < 4; ++j) {
      Og[baseA + j * 16 + l15] = f2bf(oA[j][r] * invA);
      Og[baseB + j * 16 + l15] = f2bf(oB[j][r] * invB);
    }
  }
}

// ----------------------------------------------------------------- launch
extern "C" void kernel_launch(void* const* d_in, const int* in_sizes, int n_in,
                              void* d_out, int out_size, void* d_ws, size_t ws_size,
                              hipStream_t stream)
{
  const float* q  = (const float*)d_in[0];
  const float* k  = (const float*)d_in[1];
  const float* v  = (const float*)d_in[2];
  // d_in[3] = mask (causal by construction, unused)
  const float* wq = (const float*)d_in[4];
  const float* bq = (const float*)d_in[5];
  const float* wk = (const float*)d_in[6];
  const float* bk = (const float*)d_in[7];
  const float* wv = (const float*)d_in[8];
  const float* bv = (const float*)d_in[9];
  const float* wo = (const float*)d_in[10];
  const float* bo = (const float*)d_in[11];
  u16* ws = (u16*)d_ws;
  float* out = (float*)d_out;

  cast_all<<<16384, 256, 0, stream>>>(
      (const float4*)q, (const float4*)k, (const float4*)v,
      (const float4*)wq, (const float4*)wk, (const float4*)wv, (const float4*)wo,
      (ushort4*)ws);
  proj_gemm<<<768, 256, 0, stream>>>(ws, bq, bk, bv);
  flash_attn<<<dim3(16, 32), 256, 0, stream>>>(ws);
  out_gemm<<<1024, 256, 0, stream>>>(ws, bo, out);
}

// Round 9
// 228.933 us; speedup vs baseline: 1.0635x; 1.0144x over previous
//
#include <hip/hip_runtime.h>

typedef unsigned short u16;
typedef __bf16 bf16x8 __attribute__((ext_vector_type(8)));
typedef u16 u16x8 __attribute__((ext_vector_type(8)));
typedef float f32x4 __attribute__((ext_vector_type(4)));

// ws layout (u16 units): qb,kb,vb | wqb,wkb,wvb,wob | Qp,Kp,Vt | O
constexpr size_t WQo = 12582912;   // 3 * 4194304
constexpr size_t WOo = 15728640;   // WQo + 3 * 1048576
constexpr size_t QPo = 16777216;
constexpr size_t KPo = 20971520;
constexpr size_t VTo = 25165824;
constexpr size_t OOo = 29360128;   // total 33554432 u16 = 64 MB

#define GLD(g, l) __builtin_amdgcn_global_load_lds( \
    (const __attribute__((address_space(1))) void*)(g), \
    (__attribute__((address_space(3))) void*)(l), 16, 0, 0)

__device__ __forceinline__ u16 f2bf(float f) {
  unsigned u = __builtin_bit_cast(unsigned, f);
  u += 0x7fffu + ((u >> 16) & 1u);
  return (u16)(u >> 16);
}

__device__ __forceinline__ f32x4 zero4() {
  f32x4 z = {0.f, 0.f, 0.f, 0.f};
  return z;
}

__device__ __forceinline__ f32x4 mfma16(u16x8 a, u16x8 b, f32x4 c) {
  return __builtin_amdgcn_mfma_f32_16x16x32_bf16(
      __builtin_bit_cast(bf16x8, a), __builtin_bit_cast(bf16x8, b), c, 0, 0, 0);
}

// ---------------------------------------------------------------- cast kernel
__global__ __launch_bounds__(256) void cast_all(
    const float4* __restrict__ q, const float4* __restrict__ k, const float4* __restrict__ v,
    const float4* __restrict__ wq, const float4* __restrict__ wk,
    const float4* __restrict__ wv, const float4* __restrict__ wo,
    ushort4* __restrict__ dst)
{
  int i = blockIdx.x * 256 + threadIdx.x;
  constexpr int QN = 1048576;   // 4096*1024/4
  constexpr int WN = 262144;    // 1024*1024/4
  float4 val;
  if (i < QN)            val = q[i];
  else if (i < 2 * QN)   val = k[i - QN];
  else if (i < 3 * QN)   val = v[i - 2 * QN];
  else {
    int j = i - 3 * QN;
    if (j < WN)          val = wq[j];
    else if (j < 2 * WN) val = wk[j - WN];
    else if (j < 3 * WN) val = wv[j - 2 * WN];
    else                 val = wo[j - 3 * WN];
  }
  ushort4 o;
  o.x = f2bf(val.x); o.y = f2bf(val.y); o.z = f2bf(val.z); o.w = f2bf(val.w);
  dst[i] = o;
}

// ------------- GEMM core (BK=32, dbuf, hoisted, proven LDS geometry; R5) -----
// LDS (R3/R5, measured 0 conflicts): two matrix rows per 128 B LDS row; chunk
// c = (m&1)*4 + k4 stored at slot p = c ^ ((m>>1)&7). Double-buffered, one
// barrier per k-iter, all addresses hoisted, A staged bf16 via GLD (R6 proof:
// any VGPR-routed A path loses ~20 us to the DMA path).
// modes: 0: bf16 [B,H,S,DK]   1: bf16 [B,H,DK,S] (V^T, ushort4)   3: fp32 [M,N]
template <int TM, int BN>
__device__ __forceinline__ void gemm_core(
    const u16* __restrict__ A, const u16* __restrict__ W,
    const float* __restrict__ bias, void* __restrict__ outp,
    int m0, int n0, int mode)
{
  constexpr int Kd = 1024;
  constexpr int BM = TM * 32;
  constexpr int NJ = BN / 32;        // B fragment count per wave
  constexpr int AC = BM / 64;        // A staging GLD rounds (256 chunks each)
  constexpr int BC = BN / 64;        // B staging GLD rounds
  constexpr int ASZ = BM * 32;       // u16 per A buffer
  constexpr int BSZ = BN * 32;
  __shared__ alignas(16) u16 As[2 * ASZ];
  __shared__ alignas(16) u16 Bs[2 * BSZ];
  const int tid = threadIdx.x;
  const int wave = tid >> 6, lane = tid & 63;
  const int q4 = lane >> 4, l15 = lane & 15;
  const int wm = (wave >> 1) * (TM * 16), wn = (wave & 1) * (BN / 2);

  // hoisted staging sources (swizzled) + LDS offsets
  const u16* asrc[AC]; int adst[AC];
#pragma unroll
  for (int t = 0; t < AC; ++t) {
    const int pos = t * 256 + tid;
    const int lr = pos >> 3, p = pos & 7;
    const int c = p ^ (lr & 7);
    asrc[t] = A + (size_t)(m0 + lr * 2 + (c >> 2)) * Kd + (c & 3) * 8;
    adst[t] = pos * 8;
  }
  const u16* bsrc[BC]; int bdst[BC];
#pragma unroll
  for (int t = 0; t < BC; ++t) {
    const int pos = t * 256 + tid;
    const int lr = pos >> 3, p = pos & 7;
    const int c = p ^ (lr & 7);
    bsrc[t] = W + (size_t)(n0 + lr * 2 + (c >> 2)) * Kd + (c & 3) * 8;
    bdst[t] = pos * 8;
  }
  // hoisted fragment read offsets
  int aoff[TM], boff[NJ];
#pragma unroll
  for (int i = 0; i < TM; ++i) {
    const int m = wm + i * 16 + l15;
    const int lr = m >> 1;
    const int p = ((m & 1) * 4 + q4) ^ (lr & 7);
    aoff[i] = lr * 64 + p * 8;
  }
#pragma unroll
  for (int j = 0; j < NJ; ++j) {
    const int m = wn + j * 16 + l15;
    const int lr = m >> 1;
    const int p = ((m & 1) * 4 + q4) ^ (lr & 7);
    boff[j] = lr * 64 + p * 8;
  }

  f32x4 acc[TM][NJ];
#pragma unroll
  for (int i = 0; i < TM; ++i)
#pragma unroll
    for (int j = 0; j < NJ; ++j) acc[i][j] = zero4();

  // prologue: stage k-tile 0 into buffer 0
#pragma unroll
  for (int t = 0; t < AC; ++t) GLD(asrc[t], As + adst[t]);
#pragma unroll
  for (int t = 0; t < BC; ++t) GLD(bsrc[t], Bs + bdst[t]);

  for (int it = 0; it < 32; ++it) {
    const int buf = it & 1;
    __syncthreads();             // buffer `buf` ready; buffer buf^1 consumed
    if (it < 31) {
      const int kt = (it + 1) * 32;
      const int ob = buf ^ 1;
#pragma unroll
      for (int t = 0; t < AC; ++t) GLD(asrc[t] + kt, As + ob * ASZ + adst[t]);
#pragma unroll
      for (int t = 0; t < BC; ++t) GLD(bsrc[t] + kt, Bs + ob * BSZ + bdst[t]);
    }
    const u16* Ab = As + buf * ASZ;
    const u16* Bb = Bs + buf * BSZ;
    u16x8 af[TM], bfv[NJ];
#pragma unroll
    for (int i = 0; i < TM; ++i) af[i] = *(const u16x8*)&Ab[aoff[i]];
#pragma unroll
    for (int j = 0; j < NJ; ++j) bfv[j] = *(const u16x8*)&Bb[boff[j]];
#pragma unroll
    for (int i = 0; i < TM; ++i)
#pragma unroll
      for (int j = 0; j < NJ; ++j)
        acc[i][j] = mfma16(af[i], bfv[j], acc[i][j]);
  }

  // epilogue: C/D layout col = l15, row = q4*4 + r
#pragma unroll
  for (int i = 0; i < TM; ++i) {
    const int mb = m0 + wm + i * 16 + q4 * 4;
#pragma unroll
    for (int j = 0; j < NJ; ++j) {
      const int col = n0 + wn + j * 16 + l15;
      const float bsv = bias[col];
      if (mode == 1) {
        // V^T: r = 0..3 are consecutive s -> pack ushort4
        const int bb = mb >> 11, s = mb & 2047, hh = col >> 6, dk = col & 63;
        ushort4 pk;
        pk.x = f2bf(acc[i][j][0] + bsv);
        pk.y = f2bf(acc[i][j][1] + bsv);
        pk.z = f2bf(acc[i][j][2] + bsv);
        pk.w = f2bf(acc[i][j][3] + bsv);
        *(ushort4*)&((u16*)outp)[((size_t)(bb * 16 + hh) * 64 + dk) * 2048 + s] = pk;
      } else {
#pragma unroll
        for (int r = 0; r < 4; ++r) {
          const float val = acc[i][j][r] + bsv;
          const int m = mb + r;
          if (mode == 0) {
            const int bb = m >> 11, s = m & 2047, hh = col >> 6, dk = col & 63;
            ((u16*)outp)[((size_t)(bb * 16 + hh) * 2048 + s) * 64 + dk] = f2bf(val);
          } else {
            ((float*)outp)[(size_t)m * 1024 + col] = val;
          }
        }
      }
    }
  }
}

// 1-D grid 768. Blocks sharing an A-tile (same by) have ids congruent mod 8
// -> same XCD -> A fetched once per XCD (R3: FETCH 101 -> 37 MB).
__global__ __launch_bounds__(256) void proj_gemm(
    u16* __restrict__ ws, const float* __restrict__ bq,
    const float* __restrict__ bk, const float* __restrict__ bv)
{
  const int id = blockIdx.x;
  const int z = id >> 8, rem = id & 255;
  const int bx = rem >> 5, by = rem & 31;
  const u16* A = ws + (size_t)z * 4194304;
  const u16* W = ws + WQo + (size_t)z * 1048576;
  const float* bias = (z == 0) ? bq : ((z == 1) ? bk : bv);
  u16* outp = ws + QPo + (size_t)z * 4194304;
  gemm_core<4, 128>(A, W, bias, outp, by * 128, bx * 128, (z == 2) ? 1 : 0);
}

// R5-measured-best out config: 64x128 tiles, grid 512; same-A blocks (same by)
// congruent mod 8 -> same XCD.
__global__ __launch_bounds__(256) void out_gemm(
    const u16* __restrict__ ws, const float* __restrict__ bo, float* __restrict__ out)
{
  const int id = blockIdx.x;
  const int bx = id >> 6, by = id & 63;
  gemm_core<2, 128>(ws + OOo, ws + WOo, bo, out, by * 64, bx * 128, 3);
}

// ------------------------------------------------------------- flash attention
// Paired q-tiles: block handles q-tiles a and b=31-a over one shared K/V
// k-loop (33 k-tiles per block, perfectly balanced). No-max softmax, deferred
// l reduction, double-buffered K/V staging.
// Flat grid 512, decoded so all 16 q-blocks of one head share id&7 -> same
// XCD -> that head's K/V (512 KB; 4 heads = 2 MB < 4 MB L2) stays L2-resident
// across its 16 consumers (same trick as proj's R3 FETCH 101->37 MB).
__global__ __launch_bounds__(256) void flash_attn(u16* __restrict__ ws)
{
  constexpr int S = 2048;
  const int id = blockIdx.x;
  const int a = id >> 5;                          // 0..15
  const int b = 31 - a;                           // 16..31
  const int bh = (id & 7) * 4 + ((id >> 3) & 3);  // head group pinned to XCD
  const int bb = bh >> 4, h = bh & 15;
  const int tid = threadIdx.x;
  const int wave = tid >> 6, lane = tid & 63;
  const int q4 = lane >> 4, l15 = lane & 15;

  __shared__ u16 QsA[64 * 64];      // wave strip aliased as Ps after qfA read
  __shared__ u16 QsB[64 * 64];
  __shared__ u16 Ks[2][64 * 64];
  __shared__ u16 Vs[2][64 * 64];    // [dk][s] within tile

  const u16* Qg = ws + QPo + (size_t)bh * S * 64;
  const u16* Kg = ws + KPo + (size_t)bh * S * 64;
  const u16* Vg = ws + VTo + (size_t)bh * 64 * S;
  u16* Og = ws + OOo;

  const int ch0 = wave * 128 + lane;
  const int ch1 = ch0 + 64;
  const int r0 = ch0 >> 3, c0 = (ch0 & 7) ^ (r0 & 7);
  const int r1 = ch1 >> 3, c1 = (ch1 & 7) ^ (r1 & 7);

  GLD(Qg + (size_t)(a * 64 + r0) * 64 + c0 * 8, QsA + wave * 1024);
  GLD(Qg + (size_t)(a * 64 + r1) * 64 + c1 * 8, QsA + wave * 1024 + 512);
  GLD(Qg + (size_t)(b * 64 + r0) * 64 + c0 * 8, QsB + wave * 1024);
  GLD(Qg + (size_t)(b * 64 + r1) * 64 + c1 * 8, QsB + wave * 1024 + 512);
  GLD(Kg + (size_t)r0 * 64 + c0 * 8, Ks[0] + wave * 1024);
  GLD(Kg + (size_t)r1 * 64 + c1 * 8, Ks[0] + wave * 1024 + 512);
  GLD(Vg + (size_t)r0 * S + c0 * 8, Vs[0] + wave * 1024);
  GLD(Vg + (size_t)r1 * S + c1 * 8, Vs[0] + wave * 1024 + 512);
  __syncthreads();

  u16x8 qfA[2], qfB[2];
  {
    const int row = wave * 16 + l15;
#pragma unroll
    for (int kk = 0; kk < 2; ++kk) {
      const int c = (kk * 4 + q4) ^ (row & 7);
      qfA[kk] = *(const u16x8*)&QsA[row * 64 + c * 8];
      qfB[kk] = *(const u16x8*)&QsB[row * 64 + c * 8];
    }
  }
  u16* Ps = QsA + wave * 1024;   // wave's own Q strip, consumed above

  f32x4 oA[4], oB[4];
  float lA[4], lB[4];
#pragma unroll
  for (int j = 0; j < 4; ++j) { oA[j] = zero4(); oB[j] = zero4(); }
#pragma unroll
  for (int r = 0; r < 4; ++r) { lA[r] = 0.f; lB[r] = 0.f; }

  for (int kt = 0; kt <= b; ++kt) {
    const u16* Ksb = Ks[kt & 1];
    const u16* Vsb = Vs[kt & 1];
    if (kt < b) {
      const u16* Kt = Kg + (size_t)(kt + 1) * 64 * 64;
      u16* Kd = Ks[(kt + 1) & 1];
      u16* Vd = Vs[(kt + 1) & 1];
      GLD(Kt + (size_t)r0 * 64 + c0 * 8, Kd + wave * 1024);
      GLD(Kt + (size_t)r1 * 64 + c1 * 8, Kd + wave * 1024 + 512);
      GLD(Vg + (size_t)r0 * S + (kt + 1) * 64 + c0 * 8, Vd + wave * 1024);
      GLD(Vg + (size_t)r1 * S + (kt + 1) * 64 + c1 * 8, Vd + wave * 1024 + 512);
    }

    auto process = [&](const u16x8* qf, f32x4* o_acc, float* l_p, int qt, bool diag) {
      f32x4 sf[4];
#pragma unroll
      for (int j = 0; j < 4; ++j) {
        f32x4 z = zero4();
        const int row = j * 16 + l15;
#pragma unroll
        for (int kk = 0; kk < 2; ++kk) {
          const int c = (kk * 4 + q4) ^ (row & 7);
          z = mfma16(qf[kk], *(const u16x8*)&Ksb[row * 64 + c * 8], z);
        }
        sf[j] = z;
      }
      if (diag) {
        const int rowg0 = qt * 64 + wave * 16 + q4 * 4;
#pragma unroll
        for (int j = 0; j < 4; ++j) {
          const int colg = kt * 64 + j * 16 + l15;
#pragma unroll
          for (int r = 0; r < 4; ++r) {
            float val = sf[j][r] * 0.125f;
            if (colg > rowg0 + r) val = -__builtin_inff();
            sf[j][r] = __expf(val);
          }
        }
      } else {
#pragma unroll
        for (int j = 0; j < 4; ++j)
#pragma unroll
          for (int r = 0; r < 4; ++r)
            sf[j][r] = __expf(sf[j][r] * 0.125f);
      }
#pragma unroll
      for (int j = 0; j < 4; ++j)
#pragma unroll
        for (int r = 0; r < 4; ++r) l_p[r] += sf[j][r];

#pragma unroll
      for (int j = 0; j < 4; ++j)
#pragma unroll
        for (int r = 0; r < 4; ++r) {
          const int m = q4 * 4 + r;
          const int srow = j * 16 + l15;
          const int pos = m * 64 + (((srow >> 3) ^ (m & 7)) << 3) + (srow & 7);
          Ps[pos] = f2bf(sf[j][r]);
        }
      u16x8 pf[2];
#pragma unroll
      for (int kk = 0; kk < 2; ++kk) {
        const int c = (kk * 4 + q4) ^ (l15 & 7);
        pf[kk] = *(const u16x8*)&Ps[l15 * 64 + c * 8];
      }
#pragma unroll
      for (int j = 0; j < 4; ++j) {
        const int row = j * 16 + l15;   // dk row of Vs
#pragma unroll
        for (int kk = 0; kk < 2; ++kk) {
          const int c = (kk * 4 + q4) ^ (row & 7);
          o_acc[j] = mfma16(pf[kk], *(const u16x8*)&Vsb[row * 64 + c * 8], o_acc[j]);
        }
      }
    };

    process(qfB, oB, lB, b, kt == b);
    if (kt <= a) process(qfA, oA, lA, a, kt == a);
    __syncthreads();
  }

#pragma unroll
  for (int off = 1; off < 16; off <<= 1)
#pragma unroll
    for (int r = 0; r < 4; ++r) {
      lA[r] += __shfl_xor(lA[r], off, 64);
      lB[r] += __shfl_xor(lB[r], off, 64);
    }

#pragma unroll
  for (int r = 0; r < 4; ++r) {
    const float invA = 1.f / lA[r];
    const float invB = 1.f / lB[r];
    const int sA = a * 64 + wave * 16 + q4 * 4 + r;
    const int sB = b * 64 + wave * 16 + q4 * 4 + r;
    const size_t baseA = ((size_t)(bb * 2048 + sA)) * 1024 + h * 64;
    const size_t baseB = ((size_t)(bb * 2048 + sB)) * 1024 + h * 64;
#pragma unroll
    for (int j = 0; j < 4; ++j) {
      Og[baseA + j * 16 + l15] = f2bf(oA[j][r] * invA);
      Og[baseB + j * 16 + l15] = f2bf(oB[j][r] * invB);
    }
  }
}

// ----------------------------------------------------------------- launch
extern "C" void kernel_launch(void* const* d_in, const int* in_sizes, int n_in,
                              void* d_out, int out_size, void* d_ws, size_t ws_size,
                              hipStream_t stream)
{
  const float* q  = (const float*)d_in[0];
  const float* k  = (const float*)d_in[1];
  const float* v  = (const float*)d_in[2];
  // d_in[3] = mask (causal by construction, unused)
  const float* wq = (const float*)d_in[4];
  const float* bq = (const float*)d_in[5];
  const float* wk = (const float*)d_in[6];
  const float* bk = (const float*)d_in[7];
  const float* wv = (const float*)d_in[8];
  const float* bv = (const float*)d_in[9];
  const float* wo = (const float*)d_in[10];
  const float* bo = (const float*)d_in[11];
  u16* ws = (u16*)d_ws;
  float* out = (float*)d_out;

  cast_all<<<16384, 256, 0, stream>>>(
      (const float4*)q, (const float4*)k, (const float4*)v,
      (const float4*)wq, (const float4*)wk, (const float4*)wv, (const float4*)wo,
      (ushort4*)ws);
  proj_gemm<<<768, 256, 0, stream>>>(ws, bq, bk, bv);
  flash_attn<<<512, 256, 0, stream>>>(ws);
  out_gemm<<<512, 256, 0, stream>>>(ws, bo, out);
}